// Round 15
// baseline (4529.019 us; speedup 1.0000x reference)
//
#include <hip/hip_runtime.h>
#include <stdint.h>

namespace {
constexpr int kB = 64, kT = 200;
constexpr int kNin = 700, kNs = 50, kNz = 100, kNh = 512, kNho = 100, kNout = 20;
constexpr int kQN = 4;                  // blocks per sample (column-split)
constexpr int kHistW = 21;              // padded history row (u64); 8 used
constexpr int kZW = 104;                // padded z-index row (u16)
constexpr float kDecay = 0.95f, kThresh = 0.5f, kRefrac = 2.0f;
constexpr unsigned kTag = 0x5A5B0000u;  // never 0 / 0xAAAAAAAA
constexpr size_t kFlagBytes = 256ull * 4 * 4;                     // 4 KB
constexpr size_t kBufBytes  = 2ull * 256 * 128 * 4;               // 256 KB each
constexpr size_t kWsBytes = kFlagBytes + 2 * kBufBytes;
}

#define AGT __HIP_MEMORY_SCOPE_AGENT

// Relaxed AGENT-scope atomic RMWs: cross-XCD coherent at the fabric point,
// no cache-invalidation side effects (weights stay L2-resident).
__device__ __forceinline__ void st_u32(unsigned* p, unsigned v) {
    (void)__hip_atomic_exchange(p, v, __ATOMIC_RELAXED, AGT);
}
__device__ __forceinline__ unsigned ld_u32(unsigned* p) {
    return __hip_atomic_fetch_add(p, 0u, __ATOMIC_RELAXED, AGT);
}
__device__ __forceinline__ float ld_f32b(unsigned* p) {
    return __uint_as_float(ld_u32(p));
}
__device__ __forceinline__ void drain_vmem() {
    asm volatile("s_waitcnt vmcnt(0)" ::: "memory");
}

// Adaptive-LIF update (REST=RESET=0, DT=1).
__device__ __forceinline__ void lif(float& v, float& r, float x, bool& spk) {
    r = fmaxf(r - 1.0f, 0.0f);
    v = kDecay * v + (r <= 0.0f ? x : 0.0f);
    spk = (v >= kThresh);
    if (spk) { v = 0.0f; r = kRefrac; }
}

__device__ __forceinline__ float rowsum(const unsigned short* lst, int cnt,
                                        const float* __restrict__ W, int ld, int j) {
    float a0 = 0.f, a1 = 0.f, a2 = 0.f, a3 = 0.f;
    int i = 0;
    for (; i + 4 <= cnt; i += 4) {
        a0 += W[lst[i] * ld + j];
        a1 += W[lst[i + 1] * ld + j];
        a2 += W[lst[i + 2] * ld + j];
        a3 += W[lst[i + 3] * ld + j];
    }
    for (; i < cnt; ++i) a0 += W[lst[i] * ld + j];
    return (a0 + a1) + (a2 + a3);
}

__device__ __forceinline__ float rowsum8(const unsigned short* lst, int cnt,
                                         const float* __restrict__ W, int ld, int j) {
    float a0=0,a1=0,a2=0,a3=0,a4=0,a5=0,a6=0,a7=0;
    int i = 0;
    for (; i + 8 <= cnt; i += 8) {
        a0 += W[lst[i] * ld + j];     a1 += W[lst[i+1] * ld + j];
        a2 += W[lst[i+2] * ld + j];   a3 += W[lst[i+3] * ld + j];
        a4 += W[lst[i+4] * ld + j];   a5 += W[lst[i+5] * ld + j];
        a6 += W[lst[i+6] * ld + j];   a7 += W[lst[i+7] * ld + j];
    }
    for (; i < cnt; ++i) a0 += W[lst[i] * ld + j];
    return ((a0 + a1) + (a2 + a3)) + ((a4 + a5) + (a6 + a7));
}

__global__ __launch_bounds__(512, 1)
void snn_seq(const float* __restrict__ x_in, const float* __restrict__ W_i,
             const float* __restrict__ W_z, const float* __restrict__ W_c,
             const float* __restrict__ W_h, const float* __restrict__ W_ho,
             const float* __restrict__ W_o, const float* __restrict__ lam_p,
             const float* __restrict__ eta_p, float* __restrict__ out,
             unsigned* __restrict__ flags, unsigned* __restrict__ preb,
             unsigned* __restrict__ czb) {
    __shared__ unsigned long long hist[kT][kHistW];   // 33600 B
    __shared__ float xibuf[kT * kNs];                 // 40000 B (prologue only)
    __shared__ unsigned short zidx[kT][kZW];          // 41600 B (prologue-built)
    __shared__ int zcnt[kT];                          // 800
    __shared__ unsigned long long zmask[kT][2];       // 3200
    __shared__ unsigned long long smask[kT];          // 1600
    __shared__ float lampow[kT];                      // 800
    __shared__ float ck[kT];                          // 800
    __shared__ __align__(16) float prevh[kNh];        // 2048 (FULL, locally computed)
    __shared__ float fpart[kQN][128];                 // 2048
    __shared__ float czpart[kQN][128];                // 2048
    __shared__ float pre_l[kNh];                      // 2048 (full preacts)
    __shared__ float cz_l[kNh];                       // 2048 (full cz)
    __shared__ float hored[5][kNho];                  // 2000
    __shared__ unsigned short idx_h[kNh], idx_o[kNho];
    __shared__ unsigned short idx_sb[5][kNs];
    __shared__ int cnt_sb[5];
    __shared__ int cnt_h;
    // ~134 KB LDS -> 1 block/CU; 512 threads (sane RA per rounds 7/9/12)

    const int tid = threadIdx.x;
    const int lane = tid & 63;
    const int wave = tid >> 6;                // 0..7
    const int s = blockIdx.x & 63;            // sample
    const int q = blockIdx.x >> 6;            // column-quarter 0..3
    const int sB = s * kQN;
    const int kq = tid >> 7, cl = tid & 127;  // row-quarter / own-column index
    const int col = (q << 7) + cl;            // global h column owned in F
    const float lam = lam_p[0], eta = eta_p[0];

    // ================= prologue (round-12 proven) =================
    if (tid == 0) {
        float p = 1.0f;
        for (int i = 0; i < kT; ++i) { lampow[i] = p; p *= lam; }
    }
    prevh[tid] = 0.0f;
    if (tid < 500) {                          // xi = x@W_i for all t
        const int jj = tid % kNs;
        const int tslot = tid / kNs;          // 0..9
        const float* wcol = W_i + jj;
        const size_t str10 = (size_t)10 * kB * kNin;
        for (int p = 0; p < 5; ++p) {
            const int tb = tslot + 40 * p;
            const float* x0 = x_in + ((size_t)tb * kB + s) * kNin;
            float a0 = 0.f, a1 = 0.f, a2 = 0.f, a3 = 0.f;
            for (int i = 0; i < kNin; ++i) {
                const float w = wcol[i * kNs];
                a0 = fmaf(x0[i], w, a0);
                a1 = fmaf(x0[str10 + i], w, a1);
                a2 = fmaf(x0[2 * str10 + i], w, a2);
                a3 = fmaf(x0[3 * str10 + i], w, a3);
            }
            xibuf[(tb + 0) * kNs + jj] = a0;
            xibuf[(tb + 10) * kNs + jj] = a1;
            xibuf[(tb + 20) * kNs + jj] = a2;
            xibuf[(tb + 30) * kNs + jj] = a3;
        }
    }
    __syncthreads();

    // s-chain (wave 0)
    if (wave == 0) {
        float vs = 0.f, rs = 0.f;
        for (int t = 0; t < kT; ++t) {
            bool sp = false;
            if (lane < kNs) lif(vs, rs, xibuf[t * kNs + lane], sp);
            const unsigned long long sm = __ballot(sp);
            if (lane == 0) smask[t] = sm;
        }
    }
    __syncthreads();

    // z-trains: zx matvecs t-parallel in chunks (xibuf reused), z-LIF chain on wave 0
    {
        float vz0 = 0.f, rz0 = 0.f, vz1 = 0.f, rz1 = 0.f;
        for (int c = 0; c < 4; ++c) {
            for (int sp = 0; sp < 10; ++sp) {
                if (tid < 250) {
                    const int r = tid / kNs, bp = tid % kNs;
                    const unsigned long long m = smask[50 * c + 5 * sp + r];
                    if ((m >> bp) & 1)
                        idx_sb[r][__popcll(m & ((1ull << bp) - 1))] = (unsigned short)bp;
                    if (bp == 0) cnt_sb[r] = __popcll(m);
                }
                __syncthreads();
                if (tid < 500) {
                    const int r = tid / kNz, colz = tid % kNz;
                    xibuf[(5 * sp + r) * kNz + colz] =
                        rowsum(idx_sb[r], cnt_sb[r], W_z, kNz, colz);
                }
                __syncthreads();
            }
            if (wave == 0) {
                for (int i = 0; i < 50; ++i) {
                    bool z0 = false, z1 = false;
                    if (lane < kNs) {
                        lif(vz0, rz0, xibuf[i * kNz + lane], z0);
                        lif(vz1, rz1, xibuf[i * kNz + 50 + lane], z1);
                    }
                    const unsigned long long b0 = __ballot(z0);
                    const unsigned long long b1 = __ballot(z1);
                    if (lane == 0) {
                        zmask[50 * c + i][0] = b0 | ((b1 & 0x3FFFull) << 50);
                        zmask[50 * c + i][1] = b1 >> 14;
                    }
                }
            }
            __syncthreads();
        }
    }

    // zidx/zcnt for ALL steps
    for (int base = tid; base < kT * kNz; base += 512) {
        const int tt = base / kNz, zz = base - (base / kNz) * kNz;
        const int w = zz >> 6, bit = zz & 63;
        const unsigned long long mw = zmask[tt][w];
        if ((mw >> bit) & 1) {
            int pos = __popcll(mw & ((1ull << bit) - 1));
            if (w) pos += __popcll(zmask[tt][0]);
            zidx[tt][pos] = (unsigned short)zz;
        }
        if (zz == 0) zcnt[tt] = __popcll(zmask[tt][0]) + __popcll(zmask[tt][1]);
    }
    __syncthreads();

    // ================= main sequential loop =================
    float vh = 0.f, rh = 0.f;                 // replicated h state, col = tid
    float vo0 = 0.f, ro0 = 0.f, vo1 = 0.f, ro1 = 0.f, vy = 0.f, ry = 0.f;  // wave 4

    for (int t = 0; t < kT; ++t) {
        // ---- F: own 128 cols, split-K 4x128 + cz quarter (strided) ----
        {
            const float* wh = W_h + col;
            const int k0 = kq << 7;
            float a0 = 0.f, a1 = 0.f, a2 = 0.f, a3 = 0.f;
            for (int kb = k0; kb < k0 + 128; kb += 32) {
                float w[32];
#pragma unroll
                for (int u = 0; u < 32; ++u) w[u] = wh[(size_t)(kb + u) * kNh];
#pragma unroll
                for (int u = 0; u < 32; u += 4) {
                    const float4 p = *(const float4*)&prevh[kb + u];
                    a0 = fmaf(p.x, w[u + 0], a0);
                    a1 = fmaf(p.y, w[u + 1], a1);
                    a2 = fmaf(p.z, w[u + 2], a2);
                    a3 = fmaf(p.w, w[u + 3], a3);
                }
            }
            fpart[kq][cl] = (a0 + a1) + (a2 + a3);
            const int cn = zcnt[t];
            float c0 = 0.f, c1 = 0.f;
            int i = kq;
            for (; i + 4 < cn; i += 8) {
                c0 += W_c[zidx[t][i] * kNh + col];
                c1 += W_c[zidx[t][i + 4] * kNh + col];
            }
            if (i < cn) c0 += W_c[zidx[t][i] * kNh + col];
            czpart[kq][cl] = c0 + c1;
        }
        __syncthreads();  // b1

        // ---- R: reduce + publish own (preact, cz) pair ----
        if (tid < 128) {
            const float fs = (fpart[0][tid] + fpart[1][tid]) +
                             (fpart[2][tid] + fpart[3][tid]);
            const float cz = (czpart[0][tid] + czpart[1][tid]) +
                             (czpart[2][tid] + czpart[3][tid]);
            const float pa = fs + cz;
            pre_l[(q << 7) + tid] = pa;
            cz_l[(q << 7) + tid] = cz;
            const size_t off = (size_t)(((t & 1) << 8) + sB + q) * 128 + tid;
            st_u32(&preb[off], __float_as_uint(pa));
            st_u32(&czb[off], __float_as_uint(cz));
            drain_vmem();
        }
        __syncthreads();  // b2: publishes drained

        // ---- sync A (wave 0) || OY(t-1) purely local (wave 4, hidden) ----
        if (wave == 0) {
            const unsigned ftag = kTag | (unsigned)t;
            if (lane == 0) st_u32(&flags[(sB + q) * 4 + (t & 3)], ftag);
            if (lane >= 1 && lane < 4) {
                const int pb = (q + lane) & 3;
                while (ld_u32(&flags[(sB + pb) * 4 + (t & 3)]) != ftag)
                    __builtin_amdgcn_s_sleep(1);
            }
        } else if (wave == 4 && t > 0) {
            bool o0 = false, o1 = false;
            if (lane < kNs) {
                float s0 = 0.f, s1 = 0.f;
#pragma unroll
                for (int g = 0; g < 5; ++g) {
                    s0 += hored[g][lane];
                    s1 += hored[g][lane + 50];
                }
                lif(vo0, ro0, s0, o0);
                lif(vo1, ro1, s1, o1);
            }
            const unsigned long long om0 = __ballot(o0);
            const unsigned long long om1 = __ballot(o1);
            if (o0) idx_o[__popcll(om0 & ((1ull << lane) - 1))] = (unsigned short)lane;
            if (o1) idx_o[__popcll(om0) + __popcll(om1 & ((1ull << lane) - 1))] =
                (unsigned short)(lane + 50);
            const int co = __popcll(om0) + __popcll(om1);
            if (lane < kNout) {
                bool ys = false;
                lif(vy, ry, rowsum(idx_o, co, W_o, kNout, lane), ys);
                if (q == 0) out[((size_t)(t - 1) * kB + s) * kNout + lane] = ys ? 1.0f : 0.0f;
            }
        }
        __syncthreads();  // b3: peers' (preact, cz) complete; OY done

        if (tid < 384) {                      // one-shot read of peer pairs
            const int p = tid >> 7, w = tid & 127;
            const int pb = (q + 1 + p) & 3;
            const size_t off = (size_t)(((t & 1) << 8) + sB + pb) * 128 + w;
            pre_l[(pb << 7) + w] = ld_f32b(&preb[off]);
            cz_l[(pb << 7) + w] = ld_f32b(&czb[off]);
        }
        __syncthreads();  // b4: full preact + cz vectors

        // ---- LIF all 512 cols (replicated, bitwise identical) ----
        bool hspk = false;
        lif(vh, rh, pre_l[tid], hspk);
        {
            const unsigned long long hm = __ballot(hspk);
            if (lane == 0) hist[t][wave] = hm;
        }
        __syncthreads();  // b5

        // ---- ck + idx_h (replicated, cheap) ----
        if (tid <= t) {
            int d = 0;
#pragma unroll
            for (int w = 0; w < 8; ++w) d += __popcll(hist[t][w] & hist[tid][w]);
            ck[tid] = eta * lampow[t - tid] * (float)d;
        }
        {
            const unsigned long long mw = hist[t][wave];
            if ((mw >> lane) & 1) {
                int pos = __popcll(mw & ((1ull << lane) - 1));
                for (int u = 0; u < wave; ++u) pos += __popcll(hist[t][u]);
                idx_h[pos] = (unsigned short)tid;
            }
            if (tid == 0) {
                int c = 0;
#pragma unroll
                for (int u = 0; u < 8; ++u) c += __popcll(hist[t][u]);
                cnt_h = c;
            }
        }
        __syncthreads();  // b6

        // ---- S4 FULL (replicated): sparse h@W_h + full recall -> full prevh ----
        {
            const float hw = rowsum8(idx_h, cnt_h, W_h, kNh, tid);
            const int w = tid >> 6, bit = tid & 63;
            float racc = 0.f;
            for (int k = 0; k <= t; ++k)
                racc += ((hist[k][w] >> bit) & 1) ? ck[k] : 0.f;
            prevh[tid] = (hw + racc) + cz_l[tid];
        }
        __syncthreads();  // b7: full prevh(t), locally computed — no exchange

        // ---- S6 FULL (replicated): h_new @ W_ho partials (5 groups x 100) ----
        if (tid < 500) {
            const int g = tid / kNho, c = tid - g * kNho;
            const int i0 = g * 102 + (g < 2 ? g : 2);
            const int icnt = 102 + (g < 2 ? 1 : 0);
            const float* wp = W_ho + c;
            float s0 = 0.f, s1 = 0.f;
            int i = i0;
            for (; i + 2 <= i0 + icnt; i += 2) {
                s0 = fmaf(prevh[i], wp[i * kNho], s0);
                s1 = fmaf(prevh[i + 1], wp[(i + 1) * kNho], s1);
            }
            if (i < i0 + icnt) s0 = fmaf(prevh[i], wp[i * kNho], s0);
            hored[g][c] = s0 + s1;
        }
        __syncthreads();  // b8: hored(t) ready (consumed in next step's sync window)
    }

    // ---- final OY for t = kT-1: purely local ----
    if (wave == 4) {
        bool o0 = false, o1 = false;
        if (lane < kNs) {
            float s0 = 0.f, s1 = 0.f;
#pragma unroll
            for (int g = 0; g < 5; ++g) {
                s0 += hored[g][lane];
                s1 += hored[g][lane + 50];
            }
            lif(vo0, ro0, s0, o0);
            lif(vo1, ro1, s1, o1);
        }
        const unsigned long long om0 = __ballot(o0);
        const unsigned long long om1 = __ballot(o1);
        if (o0) idx_o[__popcll(om0 & ((1ull << lane) - 1))] = (unsigned short)lane;
        if (o1) idx_o[__popcll(om0) + __popcll(om1 & ((1ull << lane) - 1))] =
            (unsigned short)(lane + 50);
        const int co = __popcll(om0) + __popcll(om1);
        if (lane < kNout) {
            bool ys = false;
            lif(vy, ry, rowsum(idx_o, co, W_o, kNout, lane), ys);
            if (q == 0) out[((size_t)(kT - 1) * kB + s) * kNout + lane] = ys ? 1.0f : 0.0f;
        }
    }
}

extern "C" void kernel_launch(void* const* d_in, const int* in_sizes, int n_in,
                              void* d_out, int out_size, void* d_ws, size_t ws_size,
                              hipStream_t stream) {
    const float* x_in = (const float*)d_in[0];
    const float* W_i  = (const float*)d_in[1];
    const float* W_z  = (const float*)d_in[2];
    const float* W_c  = (const float*)d_in[3];
    const float* W_h  = (const float*)d_in[4];
    const float* W_ho = (const float*)d_in[5];
    const float* W_o  = (const float*)d_in[6];
    const float* lam  = (const float*)d_in[7];
    const float* eta  = (const float*)d_in[8];
    if (ws_size < kWsBytes) return;
    char* ws = (char*)d_ws;
    unsigned* flags = (unsigned*)ws;                                  // 4 KB
    unsigned* preb  = (unsigned*)(ws + kFlagBytes);                   // 256 KB
    unsigned* czb   = (unsigned*)(ws + kFlagBytes + kBufBytes);       // 256 KB
    hipMemsetAsync(flags, 0, kFlagBytes, stream);
    snn_seq<<<kB * kQN, 512, 0, stream>>>(x_in, W_i, W_z, W_c, W_h, W_ho, W_o,
                                          lam, eta, (float*)d_out, flags, preb, czb);
}

// Round 16
// 2499.872 us; speedup vs baseline: 1.8117x; 1.8117x over previous
//
#include <hip/hip_runtime.h>
#include <stdint.h>

namespace {
constexpr int kB = 64, kT = 200;
constexpr int kNin = 700, kNs = 50, kNz = 100, kNh = 512, kNho = 100, kNout = 20;
constexpr int kQN = 4;                  // blocks per sample (column-split)
constexpr int kHistW = 21;              // padded history row (u64); 8 used
constexpr int kZW = 104;                // padded z-index row (u16)
constexpr float kDecay = 0.95f, kThresh = 0.5f, kRefrac = 2.0f;
constexpr unsigned kTag = 0x5A5B0000u;  // never 0 / 0xAAAAAAAA
constexpr size_t kFlagBytes = 256ull * 8 * 4;                     // 8 KB
constexpr size_t kBufBytes  = 2ull * 256 * 128 * 4;               // 256 KB each
constexpr size_t kWsBytes = kFlagBytes + 3 * kBufBytes;
}

#define AGT __HIP_MEMORY_SCOPE_AGENT

// Relaxed AGENT-scope atomic RMWs: cross-XCD coherent, no cache-invalidation
// side effects. Group peers share an XCD (blockIdx ≡ mod 8) -> L2-local, cheap.
__device__ __forceinline__ void st_u32(unsigned* p, unsigned v) {
    (void)__hip_atomic_exchange(p, v, __ATOMIC_RELAXED, AGT);
}
__device__ __forceinline__ unsigned ld_u32(unsigned* p) {
    return __hip_atomic_fetch_add(p, 0u, __ATOMIC_RELAXED, AGT);
}
__device__ __forceinline__ float ld_f32b(unsigned* p) {
    return __uint_as_float(ld_u32(p));
}
__device__ __forceinline__ void drain_vmem() {
    asm volatile("s_waitcnt vmcnt(0)" ::: "memory");
}

// Adaptive-LIF update (REST=RESET=0, DT=1).
__device__ __forceinline__ void lif(float& v, float& r, float x, bool& spk) {
    r = fmaxf(r - 1.0f, 0.0f);
    v = kDecay * v + (r <= 0.0f ? x : 0.0f);
    spk = (v >= kThresh);
    if (spk) { v = 0.0f; r = kRefrac; }
}

__device__ __forceinline__ float rowsum(const unsigned short* lst, int cnt,
                                        const float* __restrict__ W, int ld, int j) {
    float a0 = 0.f, a1 = 0.f, a2 = 0.f, a3 = 0.f;
    int i = 0;
    for (; i + 4 <= cnt; i += 4) {
        a0 += W[lst[i] * ld + j];
        a1 += W[lst[i + 1] * ld + j];
        a2 += W[lst[i + 2] * ld + j];
        a3 += W[lst[i + 3] * ld + j];
    }
    for (; i < cnt; ++i) a0 += W[lst[i] * ld + j];
    return (a0 + a1) + (a2 + a3);
}

__device__ __forceinline__ float rowsum8(const unsigned short* lst, int cnt,
                                         const float* __restrict__ W, int ld, int j) {
    float a0=0,a1=0,a2=0,a3=0,a4=0,a5=0,a6=0,a7=0;
    int i = 0;
    for (; i + 8 <= cnt; i += 8) {
        a0 += W[lst[i] * ld + j];     a1 += W[lst[i+1] * ld + j];
        a2 += W[lst[i+2] * ld + j];   a3 += W[lst[i+3] * ld + j];
        a4 += W[lst[i+4] * ld + j];   a5 += W[lst[i+5] * ld + j];
        a6 += W[lst[i+6] * ld + j];   a7 += W[lst[i+7] * ld + j];
    }
    for (; i < cnt; ++i) a0 += W[lst[i] * ld + j];
    return ((a0 + a1) + (a2 + a3)) + ((a4 + a5) + (a6 + a7));
}

__global__ __launch_bounds__(512, 1)
void snn_seq(const float* __restrict__ x_in, const float* __restrict__ W_i,
             const float* __restrict__ W_z, const float* __restrict__ W_c,
             const float* __restrict__ W_h, const float* __restrict__ W_ho,
             const float* __restrict__ W_o, const float* __restrict__ lam_p,
             const float* __restrict__ eta_p, float* __restrict__ out,
             unsigned* __restrict__ flags, unsigned* __restrict__ preb,
             unsigned* __restrict__ hnb, unsigned* __restrict__ hpb) {
    __shared__ unsigned long long hist[kT][kHistW];   // 33600 B
    __shared__ float xibuf[kT * kNs];                 // 40000 B (prologue only)
    __shared__ unsigned short zidx[kT][kZW];          // 41600 B (prologue-built)
    __shared__ int zcnt[kT];                          // 800
    __shared__ unsigned long long zmask[kT][2];       // 3200
    __shared__ unsigned long long smask[kT];          // 1600
    __shared__ float lampow[kT];                      // 800
    __shared__ float ck[kT];                          // 800
    __shared__ __align__(16) float prevh[kNh];        // 2048 (full, assembled)
    __shared__ float fpart[kQN][128];                 // 2048
    __shared__ float czpart[kQN][128];                // 2048
    __shared__ float czsave[128];                     // 512
    __shared__ float ftot[kNh];                       // 2048 (full preacts)
    __shared__ float spart[kQN][128];                 // 2048
    __shared__ float hog[5][kNho];                    // 2000
    __shared__ float hopown[kNho];                    // 400
    __shared__ unsigned short idx_h[kNh], idx_o[kNho];
    __shared__ unsigned short idx_sb[5][kNs];
    __shared__ int cnt_sb[5];
    __shared__ int cnt_h;
    // ~137 KB LDS -> 1 block/CU; 512 threads (no 64-VGPR RA cap)

    const int tid = threadIdx.x;
    const int lane = tid & 63;
    const int wave = tid >> 6;                // 0..7
    const int s = blockIdx.x & 63;            // sample
    const int q = blockIdx.x >> 6;            // column-quarter 0..3
    const int sB = s * kQN;
    const int kq = tid >> 7, cl = tid & 127;  // row-quarter / own-column index
    const int col = (q << 7) + cl;            // global h column owned in F/S4
    const float lam = lam_p[0], eta = eta_p[0];

    // ================= prologue (round-12 proven) =================
    if (tid == 0) {
        float p = 1.0f;
        for (int i = 0; i < kT; ++i) { lampow[i] = p; p *= lam; }
    }
    prevh[tid] = 0.0f;
    if (tid < 500) {                          // xi = x@W_i for all t
        const int jj = tid % kNs;
        const int tslot = tid / kNs;          // 0..9
        const float* wcol = W_i + jj;
        const size_t str10 = (size_t)10 * kB * kNin;
        for (int p = 0; p < 5; ++p) {
            const int tb = tslot + 40 * p;
            const float* x0 = x_in + ((size_t)tb * kB + s) * kNin;
            float a0 = 0.f, a1 = 0.f, a2 = 0.f, a3 = 0.f;
            for (int i = 0; i < kNin; ++i) {
                const float w = wcol[i * kNs];
                a0 = fmaf(x0[i], w, a0);
                a1 = fmaf(x0[str10 + i], w, a1);
                a2 = fmaf(x0[2 * str10 + i], w, a2);
                a3 = fmaf(x0[3 * str10 + i], w, a3);
            }
            xibuf[(tb + 0) * kNs + jj] = a0;
            xibuf[(tb + 10) * kNs + jj] = a1;
            xibuf[(tb + 20) * kNs + jj] = a2;
            xibuf[(tb + 30) * kNs + jj] = a3;
        }
    }
    __syncthreads();

    // s-chain (wave 0)
    if (wave == 0) {
        float vs = 0.f, rs = 0.f;
        for (int t = 0; t < kT; ++t) {
            bool sp = false;
            if (lane < kNs) lif(vs, rs, xibuf[t * kNs + lane], sp);
            const unsigned long long sm = __ballot(sp);
            if (lane == 0) smask[t] = sm;
        }
    }
    __syncthreads();

    // z-trains: zx matvecs t-parallel in chunks (xibuf reused), z-LIF chain on wave 0
    {
        float vz0 = 0.f, rz0 = 0.f, vz1 = 0.f, rz1 = 0.f;
        for (int c = 0; c < 4; ++c) {
            for (int sp = 0; sp < 10; ++sp) {
                if (tid < 250) {
                    const int r = tid / kNs, bp = tid % kNs;
                    const unsigned long long m = smask[50 * c + 5 * sp + r];
                    if ((m >> bp) & 1)
                        idx_sb[r][__popcll(m & ((1ull << bp) - 1))] = (unsigned short)bp;
                    if (bp == 0) cnt_sb[r] = __popcll(m);
                }
                __syncthreads();
                if (tid < 500) {
                    const int r = tid / kNz, colz = tid % kNz;
                    xibuf[(5 * sp + r) * kNz + colz] =
                        rowsum(idx_sb[r], cnt_sb[r], W_z, kNz, colz);
                }
                __syncthreads();
            }
            if (wave == 0) {
                for (int i = 0; i < 50; ++i) {
                    bool z0 = false, z1 = false;
                    if (lane < kNs) {
                        lif(vz0, rz0, xibuf[i * kNz + lane], z0);
                        lif(vz1, rz1, xibuf[i * kNz + 50 + lane], z1);
                    }
                    const unsigned long long b0 = __ballot(z0);
                    const unsigned long long b1 = __ballot(z1);
                    if (lane == 0) {
                        zmask[50 * c + i][0] = b0 | ((b1 & 0x3FFFull) << 50);
                        zmask[50 * c + i][1] = b1 >> 14;
                    }
                }
            }
            __syncthreads();
        }
    }

    // zidx/zcnt for ALL steps
    for (int base = tid; base < kT * kNz; base += 512) {
        const int tt = base / kNz, zz = base - (base / kNz) * kNz;
        const int w = zz >> 6, bit = zz & 63;
        const unsigned long long mw = zmask[tt][w];
        if ((mw >> bit) & 1) {
            int pos = __popcll(mw & ((1ull << bit) - 1));
            if (w) pos += __popcll(zmask[tt][0]);
            zidx[tt][pos] = (unsigned short)zz;
        }
        if (zz == 0) zcnt[tt] = __popcll(zmask[tt][0]) + __popcll(zmask[tt][1]);
    }
    __syncthreads();

    // ================= main sequential loop =================
    float vh = 0.f, rh = 0.f;                 // replicated h state, col = tid
    float vo0 = 0.f, ro0 = 0.f, vo1 = 0.f, ro1 = 0.f, vy = 0.f, ry = 0.f;  // wave 4

    for (int t = 0; t < kT; ++t) {
        // ---- F: own 128 cols, split-K 4x128 + cz quarter (strided, ILP4) ----
        {
            const float* wh = W_h + col;
            const int k0 = kq << 7;
            float a0 = 0.f, a1 = 0.f, a2 = 0.f, a3 = 0.f;
            for (int kb = k0; kb < k0 + 128; kb += 32) {
                float w[32];
#pragma unroll
                for (int u = 0; u < 32; ++u) w[u] = wh[(size_t)(kb + u) * kNh];
#pragma unroll
                for (int u = 0; u < 32; u += 4) {
                    const float4 p = *(const float4*)&prevh[kb + u];
                    a0 = fmaf(p.x, w[u + 0], a0);
                    a1 = fmaf(p.y, w[u + 1], a1);
                    a2 = fmaf(p.z, w[u + 2], a2);
                    a3 = fmaf(p.w, w[u + 3], a3);
                }
            }
            fpart[kq][cl] = (a0 + a1) + (a2 + a3);
            const int cn = zcnt[t];
            float c0 = 0.f, c1 = 0.f, c2 = 0.f, c3 = 0.f;
            int i = kq;
            for (; i + 12 < cn; i += 16) {
                c0 += W_c[zidx[t][i] * kNh + col];
                c1 += W_c[zidx[t][i + 4] * kNh + col];
                c2 += W_c[zidx[t][i + 8] * kNh + col];
                c3 += W_c[zidx[t][i + 12] * kNh + col];
            }
            for (; i < cn; i += 4) c0 += W_c[zidx[t][i] * kNh + col];
            czpart[kq][cl] = (c0 + c1) + (c2 + c3);
        }
        __syncthreads();  // b1

        // ---- wave 0: reduce + publish + drain + flag A + poll (no extra barrier;
        //      vmcnt is per-wave)  ||  wave 4: OY(t-1) in the sync window ----
        if (wave == 0) {
#pragma unroll
            for (int h = 0; h < 2; ++h) {
                const int c = lane + h * 64;
                const float fs = (fpart[0][c] + fpart[1][c]) +
                                 (fpart[2][c] + fpart[3][c]);
                const float cz = (czpart[0][c] + czpart[1][c]) +
                                 (czpart[2][c] + czpart[3][c]);
                czsave[c] = cz;
                const float pa = fs + cz;
                ftot[(q << 7) + c] = pa;
                st_u32(&preb[(((t & 1) << 8) + sB + q) * 128 + c], __float_as_uint(pa));
            }
            drain_vmem();
            const unsigned ftag = kTag | (unsigned)t;
            if (lane == 0) st_u32(&flags[(sB + q) * 8 + (t & 3)], ftag);
            if (lane >= 1 && lane < 4) {
                const int pb = (q + lane) & 3;
                while (ld_u32(&flags[(sB + pb) * 8 + (t & 3)]) != ftag)
                    __builtin_amdgcn_s_sleep(1);
            }
        } else if (wave == 4 && t > 0) {
            const int t1 = t - 1;
            bool o0 = false, o1 = false;
            if (lane < kNs) {
                unsigned* hb = hpb + (((t1 & 1) << 8) + sB) * 128;
                const int pb0 = (q + 1) & 3, pb1 = (q + 2) & 3, pb2 = (q + 3) & 3;
                const float x00 = ld_f32b(&hb[pb0 * 128 + lane]);
                const float x10 = ld_f32b(&hb[pb1 * 128 + lane]);
                const float x20 = ld_f32b(&hb[pb2 * 128 + lane]);
                const float x01 = ld_f32b(&hb[pb0 * 128 + lane + 50]);
                const float x11 = ld_f32b(&hb[pb1 * 128 + lane + 50]);
                const float x21 = ld_f32b(&hb[pb2 * 128 + lane + 50]);
                const float w0 = hopown[lane], w1 = hopown[lane + 50];
                float p00, p10, p20, p30, p01, p11, p21, p31;
                if (q == 0) { p00=w0; p10=x00; p20=x10; p30=x20; p01=w1; p11=x01; p21=x11; p31=x21; }
                else if (q == 1) { p10=w0; p20=x00; p30=x10; p00=x20; p11=w1; p21=x01; p31=x11; p01=x21; }
                else if (q == 2) { p20=w0; p30=x00; p00=x10; p10=x20; p21=w1; p31=x01; p01=x11; p11=x21; }
                else { p30=w0; p00=x00; p10=x10; p20=x20; p31=w1; p01=x01; p11=x11; p21=x21; }
                lif(vo0, ro0, (((p00 + p10) + p20) + p30), o0);
                lif(vo1, ro1, (((p01 + p11) + p21) + p31), o1);
            }
            const unsigned long long om0 = __ballot(o0);
            const unsigned long long om1 = __ballot(o1);
            if (o0) idx_o[__popcll(om0 & ((1ull << lane) - 1))] = (unsigned short)lane;
            if (o1) idx_o[__popcll(om0) + __popcll(om1 & ((1ull << lane) - 1))] =
                (unsigned short)(lane + 50);
            const int co = __popcll(om0) + __popcll(om1);
            if (lane < kNout) {
                bool ys = false;
                lif(vy, ry, rowsum(idx_o, co, W_o, kNout, lane), ys);
                if (q == 0) out[((size_t)t1 * kB + s) * kNout + lane] = ys ? 1.0f : 0.0f;
            }
        }
        __syncthreads();  // b3: peers' preacts complete; OY done

        if (tid < 384) {                      // one-shot read of peer preacts
            const int p = tid >> 7, w = tid & 127;
            const int pb = (q + 1 + p) & 3;
            ftot[(pb << 7) + w] =
                ld_f32b(&preb[(((t & 1) << 8) + sB + pb) * 128 + w]);
        }
        __syncthreads();  // b4: full preact vector

        // ---- LIF all 512 cols (replicated, bitwise identical) ----
        bool hspk = false;
        lif(vh, rh, ftot[tid], hspk);
        {
            const unsigned long long hm = __ballot(hspk);
            if (lane == 0) hist[t][wave] = hm;
        }
        __syncthreads();  // b5

        // ---- ck + idx_h (replicated, cheap) ----
        if (tid <= t) {
            int d = 0;
#pragma unroll
            for (int w = 0; w < 8; ++w) d += __popcll(hist[t][w] & hist[tid][w]);
            ck[tid] = eta * lampow[t - tid] * (float)d;
        }
        {
            const unsigned long long mw = hist[t][wave];
            if ((mw >> lane) & 1) {
                int pos = __popcll(mw & ((1ull << lane) - 1));
                for (int u = 0; u < wave; ++u) pos += __popcll(hist[t][u]);
                idx_h[pos] = (unsigned short)tid;
            }
            if (tid == 0) {
                int c = 0;
#pragma unroll
                for (int u = 0; u < 8; ++u) c += __popcll(hist[t][u]);
                cnt_h = c;
            }
        }
        __syncthreads();  // b6

        // ---- S4: own 128 cols, sparse rows quarter (ILP8) + recall k-quarter ----
        {
            const int ch = cnt_h;
            const int rlo = (ch * kq) >> 2, rhi = (ch * (kq + 1)) >> 2;
            float hw = rowsum8(idx_h + rlo, rhi - rlo, W_h, kNh, col);
            const int len = t + 1;
            const int klo = (len * kq) >> 2, khi = (len * (kq + 1)) >> 2;
            const int w = col >> 6, bit = col & 63;
            float racc = 0.f;
            for (int k = klo; k < khi; ++k)
                racc += ((hist[k][w] >> bit) & 1) ? ck[k] : 0.f;
            spart[kq][cl] = hw + racc;
        }
        __syncthreads();  // b7

        // ---- S5: finalize own h_new slice (LDS only) ----
        if (tid < 128) {
            const float hn = (spart[0][tid] + spart[1][tid]) +
                             (spart[2][tid] + spart[3][tid]) + czsave[tid];
            prevh[(q << 7) + tid] = hn;
        }
        __syncthreads();  // b8: own prevh slice visible for S6

        // ---- S6: own 128 rows x 100 cols partial of h_new @ W_ho (ILP4) ----
        if (tid < 500) {
            const int g = tid / kNho, c = tid - g * kNho;
            const int rl0 = (g < 3) ? 26 * g : (g == 3 ? 78 : 103);
            const int n = (g < 3) ? 26 : 25;
            const int base = (q << 7) + rl0;
            const float* wp = W_ho + c;
            float s0 = 0.f, s1 = 0.f, s2 = 0.f, s3 = 0.f;
            int i = 0;
            for (; i + 4 <= n; i += 4) {
                s0 = fmaf(prevh[base + i],     wp[(base + i) * kNho],     s0);
                s1 = fmaf(prevh[base + i + 1], wp[(base + i + 1) * kNho], s1);
                s2 = fmaf(prevh[base + i + 2], wp[(base + i + 2) * kNho], s2);
                s3 = fmaf(prevh[base + i + 3], wp[(base + i + 3) * kNho], s3);
            }
            for (; i < n; ++i) s0 = fmaf(prevh[base + i], wp[(base + i) * kNho], s0);
            hog[g][c] = (s0 + s1) + (s2 + s3);
        }
        __syncthreads();  // b9

        // ---- wave 0: publish hnb + hop + drain + flag B + poll (per-wave vmcnt) ----
        if (wave == 0) {
#pragma unroll
            for (int h = 0; h < 2; ++h) {
                const int c = lane + h * 64;
                st_u32(&hnb[(((t & 1) << 8) + sB + q) * 128 + c],
                       __float_as_uint(prevh[(q << 7) + c]));
            }
            if (lane < 50) {
#pragma unroll
                for (int h = 0; h < 2; ++h) {
                    const int c = lane + h * 50;
                    const float hv = ((hog[0][c] + hog[1][c]) +
                                      (hog[2][c] + hog[3][c])) + hog[4][c];
                    hopown[c] = hv;
                    st_u32(&hpb[(((t & 1) << 8) + sB + q) * 128 + c],
                           __float_as_uint(hv));
                }
            }
            drain_vmem();
            const unsigned ftag = kTag | (unsigned)t;
            if (lane == 0) st_u32(&flags[(sB + q) * 8 + 4 + (t & 3)], ftag);
            if (lane >= 1 && lane < 4) {
                const int pb = (q + lane) & 3;
                while (ld_u32(&flags[(sB + pb) * 8 + 4 + (t & 3)]) != ftag)
                    __builtin_amdgcn_s_sleep(1);
            }
        }
        __syncthreads();  // b11: peers' h_new + hop complete; hopown ready

        if (tid < 384) {                      // one-shot read of peer h_new slices
            const int p = tid >> 7, w = tid & 127;
            const int pb = (q + 1 + p) & 3;
            prevh[(pb << 7) + w] =
                ld_f32b(&hnb[(((t & 1) << 8) + sB + pb) * 128 + w]);
        }
        __syncthreads();  // b12: full prevh(t) for next F
    }

    // ---- final OY for t = kT-1 (wave 4; peers' hop guaranteed by my sync B) ----
    if (wave == 4) {
        const int t1 = kT - 1;
        bool o0 = false, o1 = false;
        if (lane < kNs) {
            unsigned* hb = hpb + (((t1 & 1) << 8) + sB) * 128;
            const int pb0 = (q + 1) & 3, pb1 = (q + 2) & 3, pb2 = (q + 3) & 3;
            const float x00 = ld_f32b(&hb[pb0 * 128 + lane]);
            const float x10 = ld_f32b(&hb[pb1 * 128 + lane]);
            const float x20 = ld_f32b(&hb[pb2 * 128 + lane]);
            const float x01 = ld_f32b(&hb[pb0 * 128 + lane + 50]);
            const float x11 = ld_f32b(&hb[pb1 * 128 + lane + 50]);
            const float x21 = ld_f32b(&hb[pb2 * 128 + lane + 50]);
            const float w0 = hopown[lane], w1 = hopown[lane + 50];
            float p00, p10, p20, p30, p01, p11, p21, p31;
            if (q == 0) { p00=w0; p10=x00; p20=x10; p30=x20; p01=w1; p11=x01; p21=x11; p31=x21; }
            else if (q == 1) { p10=w0; p20=x00; p30=x10; p00=x20; p11=w1; p21=x01; p31=x11; p01=x21; }
            else if (q == 2) { p20=w0; p30=x00; p00=x10; p10=x20; p21=w1; p31=x01; p01=x11; p11=x21; }
            else { p30=w0; p00=x00; p10=x10; p20=x20; p31=w1; p01=x01; p11=x11; p21=x21; }
            lif(vo0, ro0, (((p00 + p10) + p20) + p30), o0);
            lif(vo1, ro1, (((p01 + p11) + p21) + p31), o1);
        }
        const unsigned long long om0 = __ballot(o0);
        const unsigned long long om1 = __ballot(o1);
        if (o0) idx_o[__popcll(om0 & ((1ull << lane) - 1))] = (unsigned short)lane;
        if (o1) idx_o[__popcll(om0) + __popcll(om1 & ((1ull << lane) - 1))] =
            (unsigned short)(lane + 50);
        const int co = __popcll(om0) + __popcll(om1);
        if (lane < kNout) {
            bool ys = false;
            lif(vy, ry, rowsum(idx_o, co, W_o, kNout, lane), ys);
            if (q == 0) out[((size_t)t1 * kB + s) * kNout + lane] = ys ? 1.0f : 0.0f;
        }
    }
}

extern "C" void kernel_launch(void* const* d_in, const int* in_sizes, int n_in,
                              void* d_out, int out_size, void* d_ws, size_t ws_size,
                              hipStream_t stream) {
    const float* x_in = (const float*)d_in[0];
    const float* W_i  = (const float*)d_in[1];
    const float* W_z  = (const float*)d_in[2];
    const float* W_c  = (const float*)d_in[3];
    const float* W_h  = (const float*)d_in[4];
    const float* W_ho = (const float*)d_in[5];
    const float* W_o  = (const float*)d_in[6];
    const float* lam  = (const float*)d_in[7];
    const float* eta  = (const float*)d_in[8];
    if (ws_size < kWsBytes) return;
    char* ws = (char*)d_ws;
    unsigned* flags = (unsigned*)ws;                                  // 8 KB
    unsigned* preb  = (unsigned*)(ws + kFlagBytes);                   // 256 KB
    unsigned* hnb   = (unsigned*)(ws + kFlagBytes + kBufBytes);       // 256 KB
    unsigned* hpb   = (unsigned*)(ws + kFlagBytes + 2 * kBufBytes);   // 256 KB
    hipMemsetAsync(flags, 0, kFlagBytes, stream);
    snn_seq<<<kB * kQN, 512, 0, stream>>>(x_in, W_i, W_z, W_c, W_h, W_ho, W_o,
                                          lam, eta, (float*)d_out, flags, preb, hnb, hpb);
}